// Round 2
// baseline (28.408 us; speedup 1.0000x reference)
//
#include <hip/hip_runtime.h>

// Proto-distance: logits[b,q,n] = -||mean_k(support[b,n,k,:]) - query[b,q,:]||^2
// B=32, N=20, K=5, NQ=300, H=256 (fixed by setup_inputs).
//
// Two kernels:
//   K1: prototypes (mean over K) -> d_ws, computed exactly once.
//   K2: distances, 1 wave per block, each lane computes 4 outputs (4q x 1n).
//       Proto + query both via global/L1 (separate pipe from LDS; no sync).

#define HDIM 256
#define NN   20
#define KK   5
#define NQ   300

// ---- K1: proto[b*NN + n][h] = mean_k support[(b*NN+n)*KK + k][h] ----
// One wave per proto row; 160 blocks x 256 threads = 640 waves.
__global__ __launch_bounds__(256) void proto_mean_kernel(
    const float* __restrict__ support,   // [B*NN*KK, HDIM]
    float* __restrict__ proto)           // [B*NN, HDIM]
{
    const int wid  = blockIdx.x * 4 + (threadIdx.x >> 6);  // proto row 0..639
    const int lane = threadIdx.x & 63;
    const float* sp = support + (size_t)wid * (KK * HDIM) + lane * 4;
    float4 acc = make_float4(0.f, 0.f, 0.f, 0.f);
    #pragma unroll
    for (int k = 0; k < KK; ++k) {
        float4 v = *reinterpret_cast<const float4*>(sp + (size_t)k * HDIM);
        acc.x += v.x; acc.y += v.y; acc.z += v.z; acc.w += v.w;
    }
    const float inv = 1.0f / KK;
    float4 r = make_float4(acc.x * inv, acc.y * inv, acc.z * inv, acc.w * inv);
    *reinterpret_cast<float4*>(proto + (size_t)wid * HDIM + lane * 4) = r;
}

// ---- K2: one wave per (batch, 12-query chunk); lane = (qg, n) ----
// Lanes 0..59 active: n = lane % 20, qg = lane / 20 (3 groups of 4 queries).
// Each lane computes out[b, qbase+qg*4+i, n] for i = 0..3.
__global__ __launch_bounds__(64) void proto_dist_kernel(
    const float* __restrict__ proto,     // [B*NN, HDIM]
    const float* __restrict__ query,     // [B*NQ, HDIM]
    float* __restrict__ out)             // [B*NQ, NN]
{
    const int b     = blockIdx.x / 25;
    const int qbase = (blockIdx.x % 25) * 12;
    const int lane  = threadIdx.x;

    if (lane < 60) {
        const int n  = lane % 20;
        const int qg = lane / 20;

        const float* pp = proto + (size_t)(b * NN + n) * HDIM;
        const float* qp = query + (size_t)(b * NQ + qbase + qg * 4) * HDIM;

        float4 a0 = make_float4(0.f, 0.f, 0.f, 0.f);
        float4 a1 = make_float4(0.f, 0.f, 0.f, 0.f);
        float4 a2 = make_float4(0.f, 0.f, 0.f, 0.f);
        float4 a3 = make_float4(0.f, 0.f, 0.f, 0.f);

        #pragma unroll 8
        for (int h = 0; h < HDIM; h += 4) {
            float4 pv = *reinterpret_cast<const float4*>(pp + h);
            float4 q0 = *reinterpret_cast<const float4*>(qp + h);
            float4 q1 = *reinterpret_cast<const float4*>(qp + HDIM + h);
            float4 q2 = *reinterpret_cast<const float4*>(qp + 2 * HDIM + h);
            float4 q3 = *reinterpret_cast<const float4*>(qp + 3 * HDIM + h);

            float d;
            d = pv.x - q0.x; a0.x += d * d;
            d = pv.y - q0.y; a0.y += d * d;
            d = pv.z - q0.z; a0.z += d * d;
            d = pv.w - q0.w; a0.w += d * d;

            d = pv.x - q1.x; a1.x += d * d;
            d = pv.y - q1.y; a1.y += d * d;
            d = pv.z - q1.z; a1.z += d * d;
            d = pv.w - q1.w; a1.w += d * d;

            d = pv.x - q2.x; a2.x += d * d;
            d = pv.y - q2.y; a2.y += d * d;
            d = pv.z - q2.z; a2.z += d * d;
            d = pv.w - q2.w; a2.w += d * d;

            d = pv.x - q3.x; a3.x += d * d;
            d = pv.y - q3.y; a3.y += d * d;
            d = pv.z - q3.z; a3.z += d * d;
            d = pv.w - q3.w; a3.w += d * d;
        }

        float s0 = a0.x + a0.y + a0.z + a0.w;
        float s1 = a1.x + a1.y + a1.z + a1.w;
        float s2 = a2.x + a2.y + a2.z + a2.w;
        float s3 = a3.x + a3.y + a3.z + a3.w;

        float* op = out + ((size_t)(b * NQ + qbase + qg * 4)) * NN + n;
        op[0 * NN] = -s0;
        op[1 * NN] = -s1;
        op[2 * NN] = -s2;
        op[3 * NN] = -s3;
    }
}

extern "C" void kernel_launch(void* const* d_in, const int* in_sizes, int n_in,
                              void* d_out, int out_size, void* d_ws, size_t ws_size,
                              hipStream_t stream) {
    const float* support = (const float*)d_in[0];
    const float* query   = (const float*)d_in[1];
    float* out   = (float*)d_out;
    float* proto = (float*)d_ws;   // 640 * 256 * 4 B = 640 KiB scratch

    const int B = in_sizes[0] / (NN * KK * HDIM);   // 32

    proto_mean_kernel<<<dim3(B * NN / 4), dim3(256), 0, stream>>>(support, proto);
    proto_dist_kernel<<<dim3(B * (NQ / 12)), dim3(64), 0, stream>>>(proto, query, out);
}

// Round 3
// 20.400 us; speedup vs baseline: 1.3926x; 1.3926x over previous
//
#include <hip/hip_runtime.h>

// Proto-distance: logits[b,q,n] = -||mean_k(support[b,n,k,:]) - query[b,q,:]||^2
//                               = 2*p.q - ||p||^2 - ||q||^2
// B=32, N=20, K=5, NQ=300, H=256.
//
// Single fused kernel, 480 blocks x 256 threads (TQ=20 queries/block):
//  Phase 1a: 20 protos -> LDS + ||p||^2 via wave reduce (redundant per block,
//            but support tile is L2-hot: 80 MB aggregate @ 34.5 TB/s ~ 2.3us).
//  Phase 1b: ||q||^2 for the block's 20 query rows (also warms L1).
//  Phase 2:  200 threads, each 2 outputs (2q x 1n): inner loop is pure fma
//            (1 LDS b128 + 2 global b128 + 8 fma per 4-elem chunk, 2 outputs).

#define HDIM 256
#define NN   20
#define KK   5
#define NQ   300
#define TQ   20
#define PAD  260                  // 260 % 32 = 4 -> proto rows spread over 8 bank groups
#define NBLK_PER_B (NQ / TQ)      // 15

typedef float f32x4 __attribute__((ext_vector_type(4)));

__global__ __launch_bounds__(256) void proto_dist_kernel(
    const float* __restrict__ support,   // [B*NN*KK, HDIM]
    const float* __restrict__ query,     // [B*NQ, HDIM]
    float* __restrict__ out)             // [B*NQ, NN]
{
    __shared__ float proto[NN * PAD];
    __shared__ float normP[NN];
    __shared__ float normQ[TQ];

    const int b     = blockIdx.x / NBLK_PER_B;
    const int qbase = (blockIdx.x % NBLK_PER_B) * TQ;
    const int tid   = threadIdx.x;
    const int wave  = tid >> 6;
    const int lane  = tid & 63;
    const int h4    = lane * 4;

    // ---- Phase 1a: proto rows + ||p||^2 ----
    #pragma unroll
    for (int i = 0; i < 5; ++i) {
        const int n = wave * 5 + i;
        const float* sp = support + ((size_t)(b * NN + n) * KK) * HDIM + h4;
        f32x4 acc = {0.f, 0.f, 0.f, 0.f};
        #pragma unroll
        for (int k = 0; k < KK; ++k) {
            f32x4 v = *reinterpret_cast<const f32x4*>(sp + k * HDIM);
            acc += v;
        }
        acc *= 0.2f;   // 1/KK
        *reinterpret_cast<f32x4*>(&proto[n * PAD + h4]) = acc;
        float s = acc.x * acc.x + acc.y * acc.y + acc.z * acc.z + acc.w * acc.w;
        #pragma unroll
        for (int m = 32; m >= 1; m >>= 1) s += __shfl_xor(s, m, 64);
        if (lane == 0) normP[n] = s;
    }

    // ---- Phase 1b: ||q||^2 for the 20 query rows (warms L1) ----
    #pragma unroll
    for (int i = 0; i < 5; ++i) {
        const int r = wave * 5 + i;
        f32x4 v = *reinterpret_cast<const f32x4*>(
            query + (size_t)(b * NQ + qbase + r) * HDIM + h4);
        float s = v.x * v.x + v.y * v.y + v.z * v.z + v.w * v.w;
        #pragma unroll
        for (int m = 32; m >= 1; m >>= 1) s += __shfl_xor(s, m, 64);
        if (lane == 0) normQ[r] = s;
    }
    __syncthreads();

    // ---- Phase 2: 200 threads, 2 outputs each (pure-fma inner loop) ----
    if (tid < 200) {
        const int qg = tid / NN;          // 0..9
        const int n  = tid % NN;
        const int q0 = qg * 2;
        const float* qp0 = query + (size_t)(b * NQ + qbase + q0) * HDIM;
        const float* qp1 = qp0 + HDIM;
        const float* pp  = &proto[n * PAD];

        f32x4 a0 = {0.f, 0.f, 0.f, 0.f};
        f32x4 a1 = {0.f, 0.f, 0.f, 0.f};
        #pragma unroll 8
        for (int h = 0; h < HDIM; h += 4) {
            f32x4 pv = *reinterpret_cast<const f32x4*>(pp + h);
            f32x4 v0 = *reinterpret_cast<const f32x4*>(qp0 + h);
            f32x4 v1 = *reinterpret_cast<const f32x4*>(qp1 + h);
            a0 += pv * v0;
            a1 += pv * v1;
        }
        const float s0 = a0.x + a0.y + a0.z + a0.w;
        const float s1 = a1.x + a1.y + a1.z + a1.w;
        const float pn = normP[n];

        float* op = out + ((size_t)(b * NQ + qbase + q0)) * NN + n;
        op[0]  = 2.f * s0 - pn - normQ[q0];
        op[NN] = 2.f * s1 - pn - normQ[q0 + 1];
    }
}

extern "C" void kernel_launch(void* const* d_in, const int* in_sizes, int n_in,
                              void* d_out, int out_size, void* d_ws, size_t ws_size,
                              hipStream_t stream) {
    const float* support = (const float*)d_in[0];
    const float* query   = (const float*)d_in[1];
    float* out = (float*)d_out;

    const int B = in_sizes[0] / (NN * KK * HDIM);       // 32
    proto_dist_kernel<<<dim3(B * NBLK_PER_B), dim3(256), 0, stream>>>(support, query, out);
}